// Round 6
// baseline (123.660 us; speedup 1.0000x reference)
//
#include <hip/hip_runtime.h>
#include <math.h>

#define BB 512
#define LL 128
#define DD 256
#define EPSN 1e-12f

#define TI 128               // i-tile and k-tile per score block

typedef float f32x4 __attribute__((ext_vector_type(4)));
typedef int   i32x4 __attribute__((ext_vector_type(4)));
typedef int   i32x8 __attribute__((ext_vector_type(8)));

// async global->LDS, 16B per lane; LDS base wave-uniform (HW adds lane*16)
#define GLD16(gp, lp) __builtin_amdgcn_global_load_lds( \
    (const __attribute__((address_space(1))) void*)(gp), \
    (__attribute__((address_space(3))) void*)(lp), 16, 0, 0)

// ---- Kernel 1: norm + normalize + cvt fp8(e4m3), piece-swizzled rows ----
// (identical to the verified R4 prep)
// 4 rows per wave: lane = (sub-row<<4) | piece. Each lane reads 64 B of fp32
// (4x float4 contiguous), 4-step 16-lane shuffle reduce for the norm, packs
// 16 fp8 bytes, writes ONE 16 B piece at slot (piece ^ (r&15)) -- the XOR
// swizzle score's fragment reads rely on (SQ_LDS_BANK_CONFLICT==0 verified).
// Rf[b][r] holds row l=r+1; Rf[b][127] zeroed (pad). Block 0 zeroes tot/pos.
__global__ __launch_bounds__(256) void prep_kernel(const float* __restrict__ in,
                                                   unsigned char* __restrict__ Af,
                                                   unsigned char* __restrict__ Rf,
                                                   float* __restrict__ totpos) {
    if (blockIdx.x == 0) {
        ((f32x4*)totpos)[threadIdx.x] = (f32x4){0.f, 0.f, 0.f, 0.f};  // 1024 floats
    }
    int wid   = threadIdx.x >> 6;
    int lane  = threadIdx.x & 63;
    int sub   = lane >> 4;             // row within wave 0..3
    int piece = lane & 15;             // 16B output piece / 64B input chunk
    int row   = blockIdx.x * 16 + wid * 4 + sub;   // 0..65535
    int b     = row >> 7;
    int l     = row & 127;

    const float4* rp = (const float4*)(in + (size_t)row * DD) + piece * 4;
    float4 v0 = rp[0], v1 = rp[1], v2 = rp[2], v3 = rp[3];

    float ss = v0.x*v0.x + v0.y*v0.y + v0.z*v0.z + v0.w*v0.w
             + v1.x*v1.x + v1.y*v1.y + v1.z*v1.z + v1.w*v1.w
             + v2.x*v2.x + v2.y*v2.y + v2.z*v2.z + v2.w*v2.w
             + v3.x*v3.x + v3.y*v3.y + v3.z*v3.z + v3.w*v3.w;
    #pragma unroll
    for (int off = 8; off; off >>= 1) ss += __shfl_xor(ss, off);  // 16-lane group
    float sc = 1.0f / fmaxf(sqrtf(ss), EPSN);

    int d0 = __builtin_amdgcn_cvt_pk_fp8_f32(v0.x * sc, v0.y * sc, 0, false);
    d0     = __builtin_amdgcn_cvt_pk_fp8_f32(v0.z * sc, v0.w * sc, d0, true);
    int d1 = __builtin_amdgcn_cvt_pk_fp8_f32(v1.x * sc, v1.y * sc, 0, false);
    d1     = __builtin_amdgcn_cvt_pk_fp8_f32(v1.z * sc, v1.w * sc, d1, true);
    int d2 = __builtin_amdgcn_cvt_pk_fp8_f32(v2.x * sc, v2.y * sc, 0, false);
    d2     = __builtin_amdgcn_cvt_pk_fp8_f32(v2.z * sc, v2.w * sc, d2, true);
    int d3 = __builtin_amdgcn_cvt_pk_fp8_f32(v3.x * sc, v3.y * sc, 0, false);
    d3     = __builtin_amdgcn_cvt_pk_fp8_f32(v3.z * sc, v3.w * sc, d3, true);
    i32x4 val = (i32x4){d0, d1, d2, d3};

    if (l == 0) {
        *(i32x4*)(Af + (size_t)b * DD + ((piece ^ (b & 15)) << 4)) = val;
        *(i32x4*)(Rf + ((size_t)b * LL + 127) * DD + ((piece ^ 15) << 4)) =
            (i32x4){0, 0, 0, 0};       // pad row
    } else {
        int r = l - 1;
        *(i32x4*)(Rf + ((size_t)b * LL + r) * DD + ((piece ^ (r & 15)) << 4)) = val;
    }
}

// ------- Kernel 2: persistent-j, MX-scaled fp8 MFMA (K=128, unit scales) -------
// 512 blocks x 512 threads = exactly 2 blocks/CU, ALL co-resident (one
// generation, 16 waves/CU). Block owns batch j: stages Rf[j] into LDS ONCE
// (cuts R LLC traffic 64->16 MB vs the 2048-block version), then loops the
// 4 i-tiles, re-staging only the 32 KB A-tile per iter (XCD-L2-hot: Af is
// 128 KB and all blocks walk i-tiles in lockstep). Per iter: 16 MFMA/wave,
// branch-free exp epilogue (pad k=127 gives exp(0)=1, cancelled by -1 init),
// per-i sums, atomicAdd. All inner code identical to the R4-verified kernel.
__global__ __launch_bounds__(512, 4) void score_kernel(const unsigned char* __restrict__ Af,
                                                       const unsigned char* __restrict__ Rf,
                                                       const int* __restrict__ label,
                                                       float* __restrict__ tot,
                                                       float* __restrict__ pos) {
    __shared__ unsigned char sA[TI * DD];   // 32 KB (swizzled rows, linear copy)
    __shared__ unsigned char sR[TI * DD];   // 32 KB
    __shared__ float         sP[TI * 2];

    const int tid = threadIdx.x;
    const int j   = blockIdx.x;

    const int lane = tid & 63;
    const int w    = tid >> 6;         // 0..7
    const int wm   = w & 3;            // i-quarter (32 rows)
    const int wn   = w >> 2;           // k-half (64 cols)
    const int rowf = lane & 15;
    const int quad = lane >> 4;

    // ---- stage R ONCE: 32 x 1KB linear async copies ----
    const unsigned char* rBase = Rf + (size_t)j * LL * DD;
    #pragma unroll
    for (int t = 0; t < 4; ++t) {
        int c = w * 4 + t;             // 1KB chunk 0..31 (4 rows each)
        GLD16(rBase + (size_t)c * 1024 + lane * 16, &sR[c * 1024]);
    }

    const int myLab = label[j];

    for (int it = 0; it < 4; ++it) {
        const int i0 = it * TI;

        // ---- stage this iter's A-tile: 32 x 1KB linear async copies ----
        #pragma unroll
        for (int t = 0; t < 4; ++t) {
            int c = w * 4 + t;
            GLD16(Af + (size_t)i0 * DD + (size_t)c * 1024 + lane * 16, &sA[c * 1024]);
        }
        __syncthreads();               // drains A (and R on first iter)

        f32x4 acc[2][4];
        #pragma unroll
        for (int a = 0; a < 2; ++a)
            #pragma unroll
            for (int b = 0; b < 4; ++b) acc[a][b] = (f32x4){0.f, 0.f, 0.f, 0.f};

        // ---- 2 K-steps of 128, 8 MFMA each; fragment reads conflict-free ----
        // A/B frag (16x16x128 f8f6f4): row/col = lane&15, k = quad*32 + byte.
        // Piece indices ks*8 + quad*2 {+1}; stored at slot (piece ^ (row&15)).
        #pragma unroll
        for (int ks = 0; ks < 2; ++ks) {
            const int o0 = (((ks * 8 + quad * 2) ^ rowf) << 4);
            const int o1 = o0 ^ 16;    // slot of piece+1 (base piece is even)
            i32x8 af[2], bf[4];
            #pragma unroll
            for (int mt = 0; mt < 2; ++mt) {
                const unsigned char* rp = &sA[(wm * 32 + mt * 16 + rowf) * DD];
                i32x4 lo = *(const i32x4*)(rp + o0);
                i32x4 hi = *(const i32x4*)(rp + o1);
                af[mt] = __builtin_shufflevector(lo, hi, 0, 1, 2, 3, 4, 5, 6, 7);
            }
            #pragma unroll
            for (int nt = 0; nt < 4; ++nt) {
                const unsigned char* rp = &sR[(wn * 64 + nt * 16 + rowf) * DD];
                i32x4 lo = *(const i32x4*)(rp + o0);
                i32x4 hi = *(const i32x4*)(rp + o1);
                bf[nt] = __builtin_shufflevector(lo, hi, 0, 1, 2, 3, 4, 5, 6, 7);
            }
            #pragma unroll
            for (int mt = 0; mt < 2; ++mt)
                #pragma unroll
                for (int nt = 0; nt < 4; ++nt)
                    acc[mt][nt] = __builtin_amdgcn_mfma_scale_f32_16x16x128_f8f6f4(
                        af[mt], bf[nt], acc[mt][nt],
                        0, 0,                 // cbsz=fp8(e4m3), blgp=fp8(e4m3)
                        0, 0x7f7f7f7f,        // scale A: e8m0 127 -> x1.0
                        0, 0x7f7f7f7f);       // scale B: x1.0
        }

        // ---- epilogue: exp + sum over this wave's 64 k values, branch-free ----
        // C/D layout: col(n)=lane&15, row(m)=quad*4+reg (verified). Global k =
        // wn*64 + nt*16 + rowf; pad k=127 (wn=1,nt=3,rowf=15) contributes
        // exp(0)=1 -> cancel with -1.0 init on its owner lane (once per i-row).
        const float sinit = (wn == 1 && rowf == 15) ? -1.0f : 0.0f;
        #pragma unroll
        for (int mt = 0; mt < 2; ++mt) {
            float sv[4];
            #pragma unroll
            for (int r = 0; r < 4; ++r) sv[r] = sinit;
            #pragma unroll
            for (int nt = 0; nt < 4; ++nt) {
                #pragma unroll
                for (int r = 0; r < 4; ++r)
                    sv[r] += __expf(acc[mt][nt][r]);
            }
            #pragma unroll
            for (int r = 0; r < 4; ++r) {
                #pragma unroll
                for (int off = 1; off < 16; off <<= 1) sv[r] += __shfl_xor(sv[r], off);
            }
            if (rowf == 0) {
                #pragma unroll
                for (int r = 0; r < 4; ++r)
                    sP[(wm * 32 + mt * 16 + quad * 4 + r) * 2 + wn] = sv[r];
            }
        }
        __syncthreads();               // sP ready; also fences sA reads vs next stage
        if (tid < TI) {
            int i = i0 + tid;
            float e = sP[tid * 2] + sP[tid * 2 + 1];
            atomicAdd(&tot[i], e);
            if (myLab == label[i]) atomicAdd(&pos[i], e);
        }
    }
}

// ---- Kernel 3: loss = mean_i( log tot[i] - log pos[i] ) ----
__global__ __launch_bounds__(256) void final_kernel(const float* __restrict__ tot,
                                                    const float* __restrict__ pos,
                                                    float* __restrict__ out) {
    int t0 = threadIdx.x, t1 = threadIdx.x + 256;
    float s = (logf(tot[t0]) - logf(pos[t0])) + (logf(tot[t1]) - logf(pos[t1]));
    #pragma unroll
    for (int off = 32; off; off >>= 1) s += __shfl_xor(s, off);
    __shared__ float sw[4];
    int wid = threadIdx.x >> 6;
    if ((threadIdx.x & 63) == 0) sw[wid] = s;
    __syncthreads();
    if (threadIdx.x == 0) out[0] = (sw[0] + sw[1] + sw[2] + sw[3]) * (1.0f / BB);
}

extern "C" void kernel_launch(void* const* d_in, const int* in_sizes, int n_in,
                              void* d_out, int out_size, void* d_ws, size_t ws_size,
                              hipStream_t stream) {
    const float* in    = (const float*)d_in[0];
    const int*   label = (const int*)d_in[1];
    float*       out   = (float*)d_out;

    unsigned char* Af  = (unsigned char*)d_ws;               // 512*256 B (128 KB)
    unsigned char* Rf  = Af + (size_t)BB * DD;               // 512*128*256 B (16 MB)
    float*         tot = (float*)(Rf + (size_t)BB * LL * DD); // 512 f32
    float*         pos = tot + BB;                            // 512 f32

    prep_kernel<<<(BB * LL) / 16, 256, 0, stream>>>(in, Af, Rf, tot);
    score_kernel<<<BB, 512, 0, stream>>>(Af, Rf, label, tot, pos);
    final_kernel<<<1, 256, 0, stream>>>(tot, pos, out);
}

// Round 7
// 116.664 us; speedup vs baseline: 1.0600x; 1.0600x over previous
//
#include <hip/hip_runtime.h>
#include <math.h>

#define BB 512
#define LL 128
#define DD 256
#define EPSN 1e-12f

#define TI 128               // i-tile and k-tile per score block

typedef float f32x4 __attribute__((ext_vector_type(4)));
typedef int   i32x4 __attribute__((ext_vector_type(4)));
typedef int   i32x8 __attribute__((ext_vector_type(8)));

// async global->LDS, 16B per lane; LDS base wave-uniform (HW adds lane*16)
#define GLD16(gp, lp) __builtin_amdgcn_global_load_lds( \
    (const __attribute__((address_space(1))) void*)(gp), \
    (__attribute__((address_space(3))) void*)(lp), 16, 0, 0)

// ---- Kernel 1: norm + normalize + cvt fp8(e4m3), half-swizzled rows ----
// 4 rows per wave: lane = (sub-row<<4) | piece. Each lane reads 64 B of fp32
// (4x float4 contiguous), 4-step 16-lane shuffle reduce for the norm, packs
// 16 fp8 bytes, writes ONE 16 B piece at slot (piece&8)|((piece^row)&7):
// XOR swizzle WITHIN each 128-B K-half, so score can stage the two K-halves
// independently (counted-vmcnt pipeline) while fragment reads stay at the
// free 2-way LDS aliasing level. Rf[b][r] holds row l=r+1; Rf[b][127]
// zeroed (pad). Block 0 zeroes tot/pos.
__global__ __launch_bounds__(256) void prep_kernel(const float* __restrict__ in,
                                                   unsigned char* __restrict__ Af,
                                                   unsigned char* __restrict__ Rf,
                                                   float* __restrict__ totpos) {
    if (blockIdx.x == 0) {
        ((f32x4*)totpos)[threadIdx.x] = (f32x4){0.f, 0.f, 0.f, 0.f};  // 1024 floats
    }
    int wid   = threadIdx.x >> 6;
    int lane  = threadIdx.x & 63;
    int sub   = lane >> 4;             // row within wave 0..3
    int piece = lane & 15;             // 16B output piece / 64B input chunk
    int row   = blockIdx.x * 16 + wid * 4 + sub;   // 0..65535
    int b     = row >> 7;
    int l     = row & 127;

    const float4* rp = (const float4*)(in + (size_t)row * DD) + piece * 4;
    float4 v0 = rp[0], v1 = rp[1], v2 = rp[2], v3 = rp[3];

    float ss = v0.x*v0.x + v0.y*v0.y + v0.z*v0.z + v0.w*v0.w
             + v1.x*v1.x + v1.y*v1.y + v1.z*v1.z + v1.w*v1.w
             + v2.x*v2.x + v2.y*v2.y + v2.z*v2.z + v2.w*v2.w
             + v3.x*v3.x + v3.y*v3.y + v3.z*v3.z + v3.w*v3.w;
    #pragma unroll
    for (int off = 8; off; off >>= 1) ss += __shfl_xor(ss, off);  // 16-lane group
    float sc = 1.0f / fmaxf(sqrtf(ss), EPSN);

    int d0 = __builtin_amdgcn_cvt_pk_fp8_f32(v0.x * sc, v0.y * sc, 0, false);
    d0     = __builtin_amdgcn_cvt_pk_fp8_f32(v0.z * sc, v0.w * sc, d0, true);
    int d1 = __builtin_amdgcn_cvt_pk_fp8_f32(v1.x * sc, v1.y * sc, 0, false);
    d1     = __builtin_amdgcn_cvt_pk_fp8_f32(v1.z * sc, v1.w * sc, d1, true);
    int d2 = __builtin_amdgcn_cvt_pk_fp8_f32(v2.x * sc, v2.y * sc, 0, false);
    d2     = __builtin_amdgcn_cvt_pk_fp8_f32(v2.z * sc, v2.w * sc, d2, true);
    int d3 = __builtin_amdgcn_cvt_pk_fp8_f32(v3.x * sc, v3.y * sc, 0, false);
    d3     = __builtin_amdgcn_cvt_pk_fp8_f32(v3.z * sc, v3.w * sc, d3, true);
    i32x4 val = (i32x4){d0, d1, d2, d3};

    if (l == 0) {
        int offA = (((piece & 8) | ((piece ^ b) & 7)) << 4);
        *(i32x4*)(Af + (size_t)b * DD + offA) = val;
        int offP = (((piece & 8) | ((piece ^ 127) & 7)) << 4);
        *(i32x4*)(Rf + ((size_t)b * LL + 127) * DD + offP) =
            (i32x4){0, 0, 0, 0};       // pad row
    } else {
        int r = l - 1;
        int offR = (((piece & 8) | ((piece ^ r) & 7)) << 4);
        *(i32x4*)(Rf + ((size_t)b * LL + r) * DD + offR) = val;
    }
}

// ------- Kernel 2: MX-scaled fp8 MFMA (K=128, unit scales), K-half pipeline ----
// R4 structure (128x128 tile, 512 threads, 2 blocks/CU, 16 waves/CU) with a
// counted-vmcnt two-stage pipeline: stage K-half-0 (4 loads/wave), issue
// K-half-1 (4 more), s_waitcnt vmcnt(4) + raw s_barrier -> K-step-0's 8 MFMAs
// run while half-1 is still in flight; vmcnt(0) + barrier before K-step-1.
// LDS layout per operand: [half][row][128 B], row swizzled within the half.
// Branch-free exp epilogue (pad k=127 gives exp(0)=1, cancelled by -1 init),
// per-i sums, atomicAdd — all R4-verified.
__global__ __launch_bounds__(512, 4) void score_kernel(const unsigned char* __restrict__ Af,
                                                       const unsigned char* __restrict__ Rf,
                                                       const int* __restrict__ label,
                                                       float* __restrict__ tot,
                                                       float* __restrict__ pos) {
    __shared__ unsigned char sA[2 * TI * 128];   // 32 KB: [h][128 rows][128 B]
    __shared__ unsigned char sR[2 * TI * 128];   // 32 KB
    __shared__ float         sP[TI * 2];

    const int tid = threadIdx.x;
    const int i0  = blockIdx.x * TI;
    const int j   = blockIdx.y;

    const int lane = tid & 63;
    const int w    = tid >> 6;         // 0..7
    const int wm   = w & 3;            // i-quarter (32 rows)
    const int wn   = w >> 2;           // k-half (64 cols)
    const int rowf = lane & 15;
    const int quad = lane >> 4;

    const unsigned char* aBase = Af + (size_t)i0 * DD;
    const unsigned char* rBase = Rf + (size_t)j * LL * DD;

    // ---- staging: per half h, chunk c covers rows [c*8, c*8+8) x 128 B ----
    // lane: row = c*8 + (lane>>3), slot = lane&7; LDS dest linear (HW +lane*16)
    const int lr = lane >> 3;
    const int ls = lane & 7;
    #pragma unroll
    for (int h = 0; h < 2; ++h) {
        #pragma unroll
        for (int t = 0; t < 2; ++t) {
            int c = w * 2 + t;         // 0..15
            GLD16(aBase + (size_t)(c * 8 + lr) * DD + h * 128 + ls * 16,
                  &sA[h * 16384 + c * 1024]);
        }
        #pragma unroll
        for (int t = 0; t < 2; ++t) {
            int c = w * 2 + t;
            GLD16(rBase + (size_t)(c * 8 + lr) * DD + h * 128 + ls * 16,
                  &sR[h * 16384 + c * 1024]);
        }
    }

    f32x4 acc[2][4];
    #pragma unroll
    for (int a = 0; a < 2; ++a)
        #pragma unroll
        for (int b = 0; b < 4; ++b) acc[a][b] = (f32x4){0.f, 0.f, 0.f, 0.f};

    // wait for half-0 only (oldest 4 of this wave's 8 loads); half-1 in flight
    asm volatile("s_waitcnt vmcnt(4)" ::: "memory");
    __builtin_amdgcn_s_barrier();
    __builtin_amdgcn_sched_barrier(0);

    // ---- K-steps: 8 MFMA each; fragment slot = (quad*2{+1}) ^ (rowf&7) ----
    #pragma unroll
    for (int ks = 0; ks < 2; ++ks) {
        const int o0 = ks * 16384 + ((((quad * 2) ^ rowf) & 7) << 4);
        const int o1 = o0 ^ 16;        // odd piece of the pair
        i32x8 af[2], bf[4];
        #pragma unroll
        for (int mt = 0; mt < 2; ++mt) {
            const unsigned char* rp = &sA[(wm * 32 + mt * 16 + rowf) * 128];
            i32x4 lo = *(const i32x4*)(rp + o0);
            i32x4 hi = *(const i32x4*)(rp + o1);
            af[mt] = __builtin_shufflevector(lo, hi, 0, 1, 2, 3, 4, 5, 6, 7);
        }
        #pragma unroll
        for (int nt = 0; nt < 4; ++nt) {
            const unsigned char* rp = &sR[(wn * 64 + nt * 16 + rowf) * 128];
            i32x4 lo = *(const i32x4*)(rp + o0);
            i32x4 hi = *(const i32x4*)(rp + o1);
            bf[nt] = __builtin_shufflevector(lo, hi, 0, 1, 2, 3, 4, 5, 6, 7);
        }
        #pragma unroll
        for (int mt = 0; mt < 2; ++mt)
            #pragma unroll
            for (int nt = 0; nt < 4; ++nt)
                acc[mt][nt] = __builtin_amdgcn_mfma_scale_f32_16x16x128_f8f6f4(
                    af[mt], bf[nt], acc[mt][nt],
                    0, 0,                 // cbsz=fp8(e4m3), blgp=fp8(e4m3)
                    0, 0x7f7f7f7f,        // scale A: e8m0 127 -> x1.0
                    0, 0x7f7f7f7f);       // scale B: x1.0
        if (ks == 0) {
            // half-1 loads fully landed (all waves) before K-step-1 reads them
            __builtin_amdgcn_sched_barrier(0);
            asm volatile("s_waitcnt vmcnt(0)" ::: "memory");
            __builtin_amdgcn_s_barrier();
            __builtin_amdgcn_sched_barrier(0);
        }
    }

    // ---- epilogue: exp + sum over this wave's 64 k values, branch-free ----
    // C/D layout: col(n)=lane&15, row(m)=quad*4+reg (verified). Global k =
    // wn*64 + nt*16 + rowf; pad k=127 (wn=1,nt=3,rowf=15) contributes
    // exp(0)=1 -> cancel with -1.0 init on its owner lane (once per i-row).
    const float sinit = (wn == 1 && rowf == 15) ? -1.0f : 0.0f;
    #pragma unroll
    for (int mt = 0; mt < 2; ++mt) {
        float sv[4];
        #pragma unroll
        for (int r = 0; r < 4; ++r) sv[r] = sinit;
        #pragma unroll
        for (int nt = 0; nt < 4; ++nt) {
            #pragma unroll
            for (int r = 0; r < 4; ++r)
                sv[r] += __expf(acc[mt][nt][r]);
        }
        #pragma unroll
        for (int r = 0; r < 4; ++r) {
            #pragma unroll
            for (int off = 1; off < 16; off <<= 1) sv[r] += __shfl_xor(sv[r], off);
        }
        if (rowf == 0) {
            #pragma unroll
            for (int r = 0; r < 4; ++r)
                sP[(wm * 32 + mt * 16 + quad * 4 + r) * 2 + wn] = sv[r];
        }
    }
    __syncthreads();
    if (tid < TI) {
        int i = i0 + tid;
        float e = sP[tid * 2] + sP[tid * 2 + 1];
        atomicAdd(&tot[i], e);
        if (label[j] == label[i]) atomicAdd(&pos[i], e);
    }
}

// ---- Kernel 3: loss = mean_i( log tot[i] - log pos[i] ) ----
__global__ __launch_bounds__(256) void final_kernel(const float* __restrict__ tot,
                                                    const float* __restrict__ pos,
                                                    float* __restrict__ out) {
    int t0 = threadIdx.x, t1 = threadIdx.x + 256;
    float s = (logf(tot[t0]) - logf(pos[t0])) + (logf(tot[t1]) - logf(pos[t1]));
    #pragma unroll
    for (int off = 32; off; off >>= 1) s += __shfl_xor(s, off);
    __shared__ float sw[4];
    int wid = threadIdx.x >> 6;
    if ((threadIdx.x & 63) == 0) sw[wid] = s;
    __syncthreads();
    if (threadIdx.x == 0) out[0] = (sw[0] + sw[1] + sw[2] + sw[3]) * (1.0f / BB);
}

extern "C" void kernel_launch(void* const* d_in, const int* in_sizes, int n_in,
                              void* d_out, int out_size, void* d_ws, size_t ws_size,
                              hipStream_t stream) {
    const float* in    = (const float*)d_in[0];
    const int*   label = (const int*)d_in[1];
    float*       out   = (float*)d_out;

    unsigned char* Af  = (unsigned char*)d_ws;               // 512*256 B (128 KB)
    unsigned char* Rf  = Af + (size_t)BB * DD;               // 512*128*256 B (16 MB)
    float*         tot = (float*)(Rf + (size_t)BB * LL * DD); // 512 f32
    float*         pos = tot + BB;                            // 512 f32

    prep_kernel<<<(BB * LL) / 16, 256, 0, stream>>>(in, Af, Rf, tot);
    score_kernel<<<dim3(BB / TI, BB), 512, 0, stream>>>(Af, Rf, label, tot, pos);
    final_kernel<<<1, 256, 0, stream>>>(tot, pos, out);
}

// Round 8
// 115.373 us; speedup vs baseline: 1.0718x; 1.0112x over previous
//
#include <hip/hip_runtime.h>
#include <math.h>

#define BB 512
#define LL 128
#define DD 256
#define EPSN 1e-12f

#define TI 128               // i-tile and k-tile per score block

typedef float f32x4 __attribute__((ext_vector_type(4)));
typedef int   i32x4 __attribute__((ext_vector_type(4)));
typedef int   i32x8 __attribute__((ext_vector_type(8)));

// async global->LDS, 16B per lane; LDS base wave-uniform (HW adds lane*16)
#define GLD16(gp, lp) __builtin_amdgcn_global_load_lds( \
    (const __attribute__((address_space(1))) void*)(gp), \
    (__attribute__((address_space(3))) void*)(lp), 16, 0, 0)

// ---- Kernel 1: norm + normalize + cvt fp8(e4m3), piece-swizzled rows ----
// 4 rows per wave: lane = (sub-row<<4) | piece. Each lane reads 64 B of fp32
// (4x float4 contiguous), 4-step 16-lane shuffle reduce for the norm, packs
// 16 fp8 bytes, writes ONE 16 B piece at slot (piece ^ (r&15)) -- the XOR
// swizzle score's 16x16x128 fragment reads rely on (bank-conflict-free,
// verified SQ_LDS_BANK_CONFLICT==0). Rf[b][r] holds row l=r+1; Rf[b][127]
// zeroed (pad, key 127&15=15). Block 0 zeroes tot/pos.
__global__ __launch_bounds__(256) void prep_kernel(const float* __restrict__ in,
                                                   unsigned char* __restrict__ Af,
                                                   unsigned char* __restrict__ Rf,
                                                   float* __restrict__ totpos) {
    if (blockIdx.x == 0) {
        ((f32x4*)totpos)[threadIdx.x] = (f32x4){0.f, 0.f, 0.f, 0.f};  // 1024 floats
    }
    int wid   = threadIdx.x >> 6;
    int lane  = threadIdx.x & 63;
    int sub   = lane >> 4;             // row within wave 0..3
    int piece = lane & 15;             // 16B output piece / 64B input chunk
    int row   = blockIdx.x * 16 + wid * 4 + sub;   // 0..65535
    int b     = row >> 7;
    int l     = row & 127;

    const float4* rp = (const float4*)(in + (size_t)row * DD) + piece * 4;
    float4 v0 = rp[0], v1 = rp[1], v2 = rp[2], v3 = rp[3];

    float ss = v0.x*v0.x + v0.y*v0.y + v0.z*v0.z + v0.w*v0.w
             + v1.x*v1.x + v1.y*v1.y + v1.z*v1.z + v1.w*v1.w
             + v2.x*v2.x + v2.y*v2.y + v2.z*v2.z + v2.w*v2.w
             + v3.x*v3.x + v3.y*v3.y + v3.z*v3.z + v3.w*v3.w;
    #pragma unroll
    for (int off = 8; off; off >>= 1) ss += __shfl_xor(ss, off);  // 16-lane group
    float sc = 1.0f / fmaxf(sqrtf(ss), EPSN);

    int d0 = __builtin_amdgcn_cvt_pk_fp8_f32(v0.x * sc, v0.y * sc, 0, false);
    d0     = __builtin_amdgcn_cvt_pk_fp8_f32(v0.z * sc, v0.w * sc, d0, true);
    int d1 = __builtin_amdgcn_cvt_pk_fp8_f32(v1.x * sc, v1.y * sc, 0, false);
    d1     = __builtin_amdgcn_cvt_pk_fp8_f32(v1.z * sc, v1.w * sc, d1, true);
    int d2 = __builtin_amdgcn_cvt_pk_fp8_f32(v2.x * sc, v2.y * sc, 0, false);
    d2     = __builtin_amdgcn_cvt_pk_fp8_f32(v2.z * sc, v2.w * sc, d2, true);
    int d3 = __builtin_amdgcn_cvt_pk_fp8_f32(v3.x * sc, v3.y * sc, 0, false);
    d3     = __builtin_amdgcn_cvt_pk_fp8_f32(v3.z * sc, v3.w * sc, d3, true);
    i32x4 val = (i32x4){d0, d1, d2, d3};

    if (l == 0) {
        *(i32x4*)(Af + (size_t)b * DD + ((piece ^ (b & 15)) << 4)) = val;
        *(i32x4*)(Rf + ((size_t)b * LL + 127) * DD + ((piece ^ 15) << 4)) =
            (i32x4){0, 0, 0, 0};       // pad row
    } else {
        int r = l - 1;
        *(i32x4*)(Rf + ((size_t)b * LL + r) * DD + ((piece ^ (r & 15)) << 4)) = val;
    }
}

// ------- Kernel 2: MX-scaled fp8 MFMA (K=128, unit scales) + exp + k-sum -------
// R1 structure (128 anchors x 128 rest rows, full K=256 staged upfront, one
// barrier) but with 512-thread blocks: same 64 KB LDS and same total traffic,
// 2 blocks/CU x 8 waves = 16 waves/CU (2x R1's latency hiding). Per wave:
// 16 MFMA (16x16x128 f8f6f4, unit scales), branch-free exp epilogue (pad
// k=127 contributes exp(0)=1, cancelled by -1 init), per-i sums, atomicAdd.
__global__ __launch_bounds__(512, 4) void score_kernel(const unsigned char* __restrict__ Af,
                                                       const unsigned char* __restrict__ Rf,
                                                       const int* __restrict__ label,
                                                       float* __restrict__ tot,
                                                       float* __restrict__ pos) {
    __shared__ unsigned char sA[TI * DD];   // 32 KB (swizzled rows, linear copy)
    __shared__ unsigned char sR[TI * DD];   // 32 KB
    __shared__ float         sP[TI * 2];

    const int tid  = threadIdx.x;
    const int i0   = blockIdx.x * TI;
    const int j    = blockIdx.y;

    const int lane = tid & 63;
    const int w    = tid >> 6;         // 0..7
    const int wm   = w & 3;            // i-quarter (32 rows)
    const int wn   = w >> 2;           // k-half (64 cols)
    const int rowf = lane & 15;
    const int quad = lane >> 4;

    const unsigned char* aBase = Af + (size_t)i0 * DD;
    const unsigned char* rBase = Rf + (size_t)j * LL * DD;

    // ---- stage ALL of K: 64 x 1KB linear async copies, one barrier ----
    #pragma unroll
    for (int t = 0; t < 4; ++t) {
        int c = w * 4 + t;             // 1KB chunk 0..31 (4 rows each)
        GLD16(aBase + (size_t)c * 1024 + lane * 16, &sA[c * 1024]);
        GLD16(rBase + (size_t)c * 1024 + lane * 16, &sR[c * 1024]);
    }

    f32x4 acc[2][4];
    #pragma unroll
    for (int a = 0; a < 2; ++a)
        #pragma unroll
        for (int b = 0; b < 4; ++b) acc[a][b] = (f32x4){0.f, 0.f, 0.f, 0.f};

    __syncthreads();

    // ---- 2 K-steps of 128, 8 MFMA each; fragment reads conflict-free ----
    // A/B frag (16x16x128 f8f6f4): row/col = lane&15, k = quad*32 + byte.
    // Piece indices ks*8 + quad*2 {+1}; stored at slot (piece ^ (row&15)).
    #pragma unroll
    for (int ks = 0; ks < 2; ++ks) {
        const int o0 = (((ks * 8 + quad * 2) ^ rowf) << 4);
        const int o1 = o0 ^ 16;        // slot of piece+1 (base piece is even)
        i32x8 af[2], bf[4];
        #pragma unroll
        for (int mt = 0; mt < 2; ++mt) {
            const unsigned char* rp = &sA[(wm * 32 + mt * 16 + rowf) * DD];
            i32x4 lo = *(const i32x4*)(rp + o0);
            i32x4 hi = *(const i32x4*)(rp + o1);
            af[mt] = __builtin_shufflevector(lo, hi, 0, 1, 2, 3, 4, 5, 6, 7);
        }
        #pragma unroll
        for (int nt = 0; nt < 4; ++nt) {
            const unsigned char* rp = &sR[(wn * 64 + nt * 16 + rowf) * DD];
            i32x4 lo = *(const i32x4*)(rp + o0);
            i32x4 hi = *(const i32x4*)(rp + o1);
            bf[nt] = __builtin_shufflevector(lo, hi, 0, 1, 2, 3, 4, 5, 6, 7);
        }
        #pragma unroll
        for (int mt = 0; mt < 2; ++mt)
            #pragma unroll
            for (int nt = 0; nt < 4; ++nt)
                acc[mt][nt] = __builtin_amdgcn_mfma_scale_f32_16x16x128_f8f6f4(
                    af[mt], bf[nt], acc[mt][nt],
                    0, 0,                 // cbsz=fp8(e4m3), blgp=fp8(e4m3)
                    0, 0x7f7f7f7f,        // scale A: e8m0 127 -> x1.0
                    0, 0x7f7f7f7f);       // scale B: x1.0
    }

    // ---- epilogue: exp + sum over this wave's 64 k values, branch-free ----
    // C/D layout: col(n)=lane&15, row(m)=quad*4+reg (verified). Global k =
    // wn*64 + nt*16 + rowf; pad k=127 (wn=1,nt=3,rowf=15) contributes
    // exp(0)=1 -> cancel with -1.0 init on its owner lane (once per i-row).
    const float sinit = (wn == 1 && rowf == 15) ? -1.0f : 0.0f;
    #pragma unroll
    for (int mt = 0; mt < 2; ++mt) {
        float sv[4];
        #pragma unroll
        for (int r = 0; r < 4; ++r) sv[r] = sinit;
        #pragma unroll
        for (int nt = 0; nt < 4; ++nt) {
            #pragma unroll
            for (int r = 0; r < 4; ++r)
                sv[r] += __expf(acc[mt][nt][r]);
        }
        #pragma unroll
        for (int r = 0; r < 4; ++r) {
            #pragma unroll
            for (int off = 1; off < 16; off <<= 1) sv[r] += __shfl_xor(sv[r], off);
        }
        if (rowf == 0) {
            #pragma unroll
            for (int r = 0; r < 4; ++r)
                sP[(wm * 32 + mt * 16 + quad * 4 + r) * 2 + wn] = sv[r];
        }
    }
    __syncthreads();
    if (tid < TI) {
        int i = i0 + tid;
        float e = sP[tid * 2] + sP[tid * 2 + 1];
        atomicAdd(&tot[i], e);
        if (label[j] == label[i]) atomicAdd(&pos[i], e);
    }
}

// ---- Kernel 3: loss = mean_i( log tot[i] - log pos[i] ) ----
__global__ __launch_bounds__(256) void final_kernel(const float* __restrict__ tot,
                                                    const float* __restrict__ pos,
                                                    float* __restrict__ out) {
    int t0 = threadIdx.x, t1 = threadIdx.x + 256;
    float s = (logf(tot[t0]) - logf(pos[t0])) + (logf(tot[t1]) - logf(pos[t1]));
    #pragma unroll
    for (int off = 32; off; off >>= 1) s += __shfl_xor(s, off);
    __shared__ float sw[4];
    int wid = threadIdx.x >> 6;
    if ((threadIdx.x & 63) == 0) sw[wid] = s;
    __syncthreads();
    if (threadIdx.x == 0) out[0] = (sw[0] + sw[1] + sw[2] + sw[3]) * (1.0f / BB);
}

extern "C" void kernel_launch(void* const* d_in, const int* in_sizes, int n_in,
                              void* d_out, int out_size, void* d_ws, size_t ws_size,
                              hipStream_t stream) {
    const float* in    = (const float*)d_in[0];
    const int*   label = (const int*)d_in[1];
    float*       out   = (float*)d_out;

    unsigned char* Af  = (unsigned char*)d_ws;               // 512*256 B (128 KB)
    unsigned char* Rf  = Af + (size_t)BB * DD;               // 512*128*256 B (16 MB)
    float*         tot = (float*)(Rf + (size_t)BB * LL * DD); // 512 f32
    float*         pos = tot + BB;                            // 512 f32

    prep_kernel<<<(BB * LL) / 16, 256, 0, stream>>>(in, Af, Rf, tot);
    score_kernel<<<dim3(BB / TI, BB), 512, 0, stream>>>(Af, Rf, label, tot, pos);
    final_kernel<<<1, 256, 0, stream>>>(tot, pos, out);
}